// Round 1
// baseline (776.092 us; speedup 1.0000x reference)
//
#include <hip/hip_runtime.h>
#include <math.h>

#define BGR 32
#define NPER0 1024
#define N0 (BGR * NPER0)
#define FDIM 128
#define EDG 524288
#define EPG (EDG / BGR)
#define K1 512
#define K2 256
#define K3 128

// ---------------------------------------------------------------------------
// CSR build per graph. Edge validity = (src[e] >= 0). Writes deg (with +1
// self loop), dinv = rsqrt(deg), rowptr/rowcnt, and csr_src (src ids bucketed
// by dst). One block per graph; edges for graph g are [g*EPG, (g+1)*EPG).
// ---------------------------------------------------------------------------
__global__ void csr_build(const int* __restrict__ src, const int* __restrict__ dst,
                          int nper,
                          float* __restrict__ deg, float* __restrict__ dinv,
                          int* __restrict__ rowptr, int* __restrict__ rowcnt,
                          int* __restrict__ csr_src) {
    __shared__ int cnt[NPER0];
    __shared__ int off[NPER0];
    __shared__ int psum[256];
    const int g = blockIdx.x, t = threadIdx.x;
    const int gnb = g * nper, ebase = g * EPG;

    for (int i = t; i < nper; i += 256) cnt[i] = 0;
    __syncthreads();
    for (int e = t; e < EPG; e += 256) {
        int s = src[ebase + e];
        if (s >= 0) atomicAdd(&cnt[dst[ebase + e] - gnb], 1);
    }
    __syncthreads();
    // exclusive scan of cnt[0..nper)
    const int S = nper >> 8;  // nper/256: 4, 2, or 1
    const int b0 = t * S;
    int loc = 0;
    for (int q = 0; q < S; q++) loc += cnt[b0 + q];
    psum[t] = loc;
    __syncthreads();
    if (t == 0) {
        int run = 0;
        for (int i = 0; i < 256; i++) { int v = psum[i]; psum[i] = run; run += v; }
    }
    __syncthreads();
    int run = psum[t];
    for (int q = 0; q < S; q++) { off[b0 + q] = run; run += cnt[b0 + q]; }
    __syncthreads();
    for (int i = t; i < nper; i += 256) {
        int c = cnt[i];
        float d = (float)c + 1.0f;
        deg[gnb + i] = d;
        dinv[gnb + i] = rsqrtf(d);
        rowptr[gnb + i] = ebase + off[i];
        rowcnt[gnb + i] = c;
    }
    __syncthreads();
    for (int i = t; i < nper; i += 256) cnt[i] = 0;  // reuse as cursor
    __syncthreads();
    for (int e = t; e < EPG; e += 256) {
        int s = src[ebase + e];
        if (s >= 0) {
            int dl = dst[ebase + e] - gnb;
            int p = atomicAdd(&cnt[dl], 1);
            csr_src[ebase + off[dl] + p] = s;
        }
    }
}

// ---------------------------------------------------------------------------
// Per-head projection: h[i, h*32+e] = sum_d x[i, h*32+d] * W[h, d, e].
// Block = 128 threads (one output feature each), 32 nodes per block.
// ---------------------------------------------------------------------------
__global__ void proj_kernel(const float* __restrict__ x, const float* __restrict__ W,
                            float* __restrict__ hp) {
    __shared__ float sW[4096];
    __shared__ float sx[32][128];
    const int t = threadIdx.x;
    const int nb = blockIdx.x * 32;
    for (int i = t; i < 4096; i += 128) sW[i] = W[i];
    for (int i = t; i < 4096; i += 128)
        sx[i >> 7][i & 127] = x[(size_t)(nb + (i >> 7)) * FDIM + (i & 127)];
    __syncthreads();
    const int h = t >> 5, e = t & 31;
    float wcol[32];
#pragma unroll
    for (int d = 0; d < 32; d++) wcol[d] = sW[h * 1024 + d * 32 + e];
    for (int nn = 0; nn < 32; nn++) {
        float acc = 0.0f;
#pragma unroll
        for (int d0 = 0; d0 < 32; d0++) {
            int d = (d0 + h * 8) & 31;  // stagger heads to spread LDS banks
            acc = fmaf(sx[nn][h * 32 + d], wcol[d], acc);
        }
        hp[(size_t)(nb + nn) * FDIM + t] = acc;
    }
}

// ---------------------------------------------------------------------------
// GCN aggregation (gather via CSR) + bias + relu.
// One block per node, 128 threads = features.
// out[i] = relu( h[i]/deg[i] + sum_j dinv[s_j]*dinv[i]*h[s_j] + b )
// ---------------------------------------------------------------------------
__global__ void agg_kernel(const float* __restrict__ hp, const float* __restrict__ b,
                           const float* __restrict__ dinv, const int* __restrict__ rowptr,
                           const int* __restrict__ rowcnt, const int* __restrict__ csr_src,
                           float* __restrict__ ha) {
    const int i = blockIdx.x;
    const int f = threadIdx.x;
    const float di = dinv[i];
    float acc = hp[(size_t)i * FDIM + f] * di * di;
    const int st = rowptr[i], c = rowcnt[i];
    for (int j = 0; j < c; j++) {
        int s = csr_src[st + j];
        acc = fmaf(hp[(size_t)s * FDIM + f], dinv[s] * di, acc);
    }
    ha[(size_t)i * FDIM + f] = fmaxf(acc + b[f], 0.0f);
}

// ---------------------------------------------------------------------------
// Attention score projection: cs[i] = sum_h att_h * pw_h where
// att_h = sum_d x[i,h*32+d]*A[h*32+d], pw_h = sum_d x[i,h*32+d]*psW[h*32+d].
// One wave (64 lanes) per node; lane covers f and f+64.
// ---------------------------------------------------------------------------
__global__ void attcs_kernel(const float* __restrict__ ha, const float* __restrict__ A,
                             const float* __restrict__ psW, float* __restrict__ cs) {
    const int wid = threadIdx.x >> 6;
    const int lane = threadIdx.x & 63;
    const int i = blockIdx.x * 4 + wid;
    float v0 = ha[(size_t)i * FDIM + lane];
    float v1 = ha[(size_t)i * FDIM + 64 + lane];
    float a0 = v0 * A[lane], p0 = v0 * psW[lane];
    float a1 = v1 * A[64 + lane], p1 = v1 * psW[64 + lane];
    for (int d = 16; d > 0; d >>= 1) {
        a0 += __shfl_down(a0, d, 32);
        p0 += __shfl_down(p0, d, 32);
        a1 += __shfl_down(a1, d, 32);
        p1 += __shfl_down(p1, d, 32);
    }
    float part = a0 * p0 + a1 * p1;  // valid at lanes 0 and 32
    part += __shfl_down(part, 32, 64);
    if (lane == 0) cs[i] = part;
}

// ---------------------------------------------------------------------------
// Fused score-aggregation + per-graph top-k (bitonic sort in LDS).
// score[i] = gcn_agg(cs)[i] + psb; keep top-k set (order irrelevant downstream).
// Writes nmap (old->new or -1), perm (new->old), mult (tanh(score)).
// ---------------------------------------------------------------------------
__global__ void topk_kernel(const float* __restrict__ cs, const float* __restrict__ dinv,
                            const int* __restrict__ rowptr, const int* __restrict__ rowcnt,
                            const int* __restrict__ csr_src, const float* __restrict__ psb,
                            int nper, int k, int* __restrict__ nmap, int* __restrict__ perm,
                            float* __restrict__ mult) {
    __shared__ float sc[NPER0];
    __shared__ unsigned long long keys[NPER0];
    const int g = blockIdx.x, t = threadIdx.x;
    const int gnb = g * nper;
    const float pb = psb[0];
    for (int i = t; i < nper; i += 256) {
        int node = gnb + i;
        float di = dinv[node];
        float acc = cs[node] * di * di;
        int st = rowptr[node], c = rowcnt[node];
        for (int j = 0; j < c; j++) {
            int s = csr_src[st + j];
            acc = fmaf(cs[s], dinv[s] * di, acc);
        }
        sc[i] = acc + pb;
    }
    __syncthreads();
    for (int i = t; i < nper; i += 256) {
        unsigned u = __float_as_uint(sc[i]);
        u = (u & 0x80000000u) ? ~u : (u | 0x80000000u);  // ascending-sortable
        keys[i] = ((unsigned long long)u << 32) | (unsigned)i;
    }
    for (int ksz = 2; ksz <= nper; ksz <<= 1) {
        for (int j = ksz >> 1; j > 0; j >>= 1) {
            __syncthreads();
            for (int i = t; i < nper; i += 256) {
                int ixj = i ^ j;
                if (ixj > i) {
                    unsigned long long a = keys[i], bb = keys[ixj];
                    bool up = ((i & ksz) == 0);
                    if ((a > bb) == up) { keys[i] = bb; keys[ixj] = a; }
                }
            }
        }
    }
    __syncthreads();
    for (int p = t; p < nper; p += 256) {
        int idx = (int)(keys[p] & 0xFFFFFFFFu);
        int node_old = gnb + idx;
        if (p >= nper - k) {
            int newid = g * k + (p - (nper - k));
            nmap[node_old] = newid;
            perm[newid] = node_old;
            mult[newid] = tanhf(sc[idx]);
        } else {
            nmap[node_old] = -1;
        }
    }
}

// ---------------------------------------------------------------------------
// Pooling gather (xn = h[perm]*tanh(score)) fused with per-graph readout
// (max & mean over kept nodes). One block per graph, 256 threads (2 halves).
// ---------------------------------------------------------------------------
__global__ void poolgather_kernel(const float* __restrict__ ha, const int* __restrict__ perm,
                                  const float* __restrict__ mult, int k,
                                  float* __restrict__ xn, float* __restrict__ r,
                                  int accumulate) {
    __shared__ float smax[128], ssum[128];
    const int g = blockIdx.x, t = threadIdx.x;
    const int f = t & 127, half = t >> 7;
    float vmax = -1e30f, vsum = 0.0f;
    for (int j = half; j < k; j += 2) {
        int newid = g * k + j;
        int old = perm[newid];
        float m = mult[newid];
        float v = ha[(size_t)old * FDIM + f] * m;
        xn[(size_t)newid * FDIM + f] = v;
        vmax = fmaxf(vmax, v);
        vsum += v;
    }
    if (half) { smax[f] = vmax; ssum[f] = vsum; }
    __syncthreads();
    if (!half) {
        vmax = fmaxf(vmax, smax[f]);
        vsum += ssum[f];
        float mean = vsum / (float)k;
        if (accumulate) {
            r[g * 256 + f] += vmax;
            r[g * 256 + 128 + f] += mean;
        } else {
            r[g * 256 + f] = vmax;
            r[g * 256 + 128 + f] = mean;
        }
    }
}

// ---------------------------------------------------------------------------
// Edge remap after pooling. Invalid edges carry src = -1 sentinel.
// ---------------------------------------------------------------------------
__global__ void remap_kernel(const int* __restrict__ src, const int* __restrict__ dst,
                             const int* __restrict__ nmap,
                             int* __restrict__ nsrc, int* __restrict__ ndst) {
    const int e = blockIdx.x * 256 + threadIdx.x;
    int so = src[e];
    int ns = (so >= 0) ? nmap[so] : -1;
    int nd = nmap[dst[e]];
    bool valid = (ns >= 0) && (nd >= 0);
    nsrc[e] = valid ? ns : -1;
    ndst[e] = valid ? nd : 0;
}

// ---------------------------------------------------------------------------
// Final MLP + log_softmax. One block per graph, 128 threads.
// ---------------------------------------------------------------------------
__global__ void final_mlp(const float* __restrict__ r,
                          const float* __restrict__ l1W, const float* __restrict__ l1b,
                          const float* __restrict__ l2W, const float* __restrict__ l2b,
                          const float* __restrict__ l3W, const float* __restrict__ l3b,
                          float* __restrict__ out) {
    __shared__ float sz[256], s1[128], s2[64], s3[10], red[2];
    const int g = blockIdx.x, t = threadIdx.x;
    sz[t] = r[g * 256 + t];
    sz[t + 128] = r[g * 256 + 128 + t];
    __syncthreads();
    float acc = l1b[t];
    for (int i = 0; i < 256; i++) acc = fmaf(sz[i], l1W[i * 128 + t], acc);
    s1[t] = fmaxf(acc, 0.0f);
    __syncthreads();
    if (t < 64) {
        float a2 = l2b[t];
        for (int i = 0; i < 128; i++) a2 = fmaf(s1[i], l2W[i * 64 + t], a2);
        s2[t] = fmaxf(a2, 0.0f);
    }
    __syncthreads();
    if (t < 10) {
        float a3 = l3b[t];
        for (int i = 0; i < 64; i++) a3 = fmaf(s2[i], l3W[i * 10 + t], a3);
        s3[t] = a3;
    }
    __syncthreads();
    if (t == 0) {
        float m = -1e30f;
        for (int c = 0; c < 10; c++) m = fmaxf(m, s3[c]);
        float sum = 0.0f;
        for (int c = 0; c < 10; c++) sum += expf(s3[c] - m);
        red[0] = m;
        red[1] = logf(sum);
    }
    __syncthreads();
    if (t < 10) out[g * 10 + t] = s3[t] - red[0] - red[1];
}

// ---------------------------------------------------------------------------
extern "C" void kernel_launch(void* const* d_in, const int* in_sizes, int n_in,
                              void* d_out, int out_size, void* d_ws, size_t ws_size,
                              hipStream_t stream) {
    const float* x    = (const float*)d_in[0];
    const int* src0   = (const int*)d_in[1];
    const int* dst0   = (const int*)d_in[2];
    const float* W1   = (const float*)d_in[3];
    const float* b1   = (const float*)d_in[4];
    const float* A1   = (const float*)d_in[5];
    const float* ps1W = (const float*)d_in[6];
    const float* ps1b = (const float*)d_in[7];
    const float* W2   = (const float*)d_in[8];
    const float* b2   = (const float*)d_in[9];
    const float* A2   = (const float*)d_in[10];
    const float* ps2W = (const float*)d_in[11];
    const float* ps2b = (const float*)d_in[12];
    const float* W3   = (const float*)d_in[13];
    const float* b3   = (const float*)d_in[14];
    const float* A3   = (const float*)d_in[15];
    const float* ps3W = (const float*)d_in[16];
    const float* ps3b = (const float*)d_in[17];
    const float* l1W  = (const float*)d_in[18];
    const float* l1b  = (const float*)d_in[19];
    const float* l2W  = (const float*)d_in[20];
    const float* l2b  = (const float*)d_in[21];
    const float* l3W  = (const float*)d_in[22];
    const float* l3b  = (const float*)d_in[23];
    float* out = (float*)d_out;

    char* ws = (char*)d_ws;
    size_t o = 0;
    auto alloc = [&](size_t bytes) -> void* {
        void* p = ws + o;
        o += (bytes + 255) & ~(size_t)255;
        return p;
    };
    float* hproj   = (float*)alloc((size_t)N0 * FDIM * 4);
    float* hact    = (float*)alloc((size_t)N0 * FDIM * 4);
    float* xn      = (float*)alloc((size_t)N0 * FDIM * 4);
    float* deg     = (float*)alloc(N0 * 4);
    float* dinv    = (float*)alloc(N0 * 4);
    int*   rowptr  = (int*)alloc(N0 * 4);
    int*   rowcnt  = (int*)alloc(N0 * 4);
    int*   csr_src = (int*)alloc(EDG * 4);
    float* cs      = (float*)alloc(N0 * 4);
    int*   nmap    = (int*)alloc(N0 * 4);
    int*   perm    = (int*)alloc(BGR * K1 * 4);
    float* mult    = (float*)alloc(BGR * K1 * 4);
    float* r       = (float*)alloc(BGR * 256 * 4);
    int*   se1     = (int*)alloc(EDG * 4);
    int*   de1     = (int*)alloc(EDG * 4);
    int*   se2     = (int*)alloc(EDG * 4);
    int*   de2     = (int*)alloc(EDG * 4);

    // ---------------- Stage 1: n=32768, nper=1024, k=512 ----------------
    csr_build<<<BGR, 256, 0, stream>>>(src0, dst0, NPER0, deg, dinv, rowptr, rowcnt, csr_src);
    proj_kernel<<<N0 / 32, 128, 0, stream>>>(x, W1, hproj);
    agg_kernel<<<N0, 128, 0, stream>>>(hproj, b1, dinv, rowptr, rowcnt, csr_src, hact);
    attcs_kernel<<<N0 / 4, 256, 0, stream>>>(hact, A1, ps1W, cs);
    topk_kernel<<<BGR, 256, 0, stream>>>(cs, dinv, rowptr, rowcnt, csr_src, ps1b,
                                         NPER0, K1, nmap, perm, mult);
    poolgather_kernel<<<BGR, 256, 0, stream>>>(hact, perm, mult, K1, xn, r, 0);
    remap_kernel<<<EDG / 256, 256, 0, stream>>>(src0, dst0, nmap, se1, de1);

    // ---------------- Stage 2: n=16384, nper=512, k=256 ----------------
    const int n1 = BGR * K1;
    csr_build<<<BGR, 256, 0, stream>>>(se1, de1, K1, deg, dinv, rowptr, rowcnt, csr_src);
    proj_kernel<<<n1 / 32, 128, 0, stream>>>(xn, W2, hproj);
    agg_kernel<<<n1, 128, 0, stream>>>(hproj, b2, dinv, rowptr, rowcnt, csr_src, hact);
    attcs_kernel<<<n1 / 4, 256, 0, stream>>>(hact, A2, ps2W, cs);
    topk_kernel<<<BGR, 256, 0, stream>>>(cs, dinv, rowptr, rowcnt, csr_src, ps2b,
                                         K1, K2, nmap, perm, mult);
    poolgather_kernel<<<BGR, 256, 0, stream>>>(hact, perm, mult, K2, xn, r, 1);
    remap_kernel<<<EDG / 256, 256, 0, stream>>>(se1, de1, nmap, se2, de2);

    // ---------------- Stage 3: n=8192, nper=256, k=128 ----------------
    const int n2 = BGR * K2;
    csr_build<<<BGR, 256, 0, stream>>>(se2, de2, K2, deg, dinv, rowptr, rowcnt, csr_src);
    proj_kernel<<<n2 / 32, 128, 0, stream>>>(xn, W3, hproj);
    agg_kernel<<<n2, 128, 0, stream>>>(hproj, b3, dinv, rowptr, rowcnt, csr_src, hact);
    attcs_kernel<<<n2 / 4, 256, 0, stream>>>(hact, A3, ps3W, cs);
    topk_kernel<<<BGR, 256, 0, stream>>>(cs, dinv, rowptr, rowcnt, csr_src, ps3b,
                                         K2, K3, nmap, perm, mult);
    poolgather_kernel<<<BGR, 256, 0, stream>>>(hact, perm, mult, K3, xn, r, 1);

    // ---------------- Final MLP ----------------
    final_mlp<<<BGR, 128, 0, stream>>>(r, l1W, l1b, l2W, l2b, l3W, l3b, out);

    (void)in_sizes; (void)n_in; (void)out_size; (void)ws_size;
}

// Round 2
// 607.272 us; speedup vs baseline: 1.2780x; 1.2780x over previous
//
#include <hip/hip_runtime.h>
#include <math.h>

#define BGR 32
#define NPER0 1024
#define N0 (BGR * NPER0)
#define FDIM 128
#define EDG 524288
#define EPG (EDG / BGR)
#define K1 512
#define K2 256
#define K3 128
#define PGJ 8  // kept nodes per poolgather block

// ---------------------------------------------------------------------------
// CSR build per graph. Edge validity = (src[e] >= 0). Writes deg (with +1
// self loop), dinv = rsqrt(deg), rowptr/rowcnt, and csr_src (src ids bucketed
// by dst). One block per graph; edges for graph g are [g*EPG, (g+1)*EPG).
// ---------------------------------------------------------------------------
__global__ void csr_build(const int* __restrict__ src, const int* __restrict__ dst,
                          int nper,
                          float* __restrict__ deg, float* __restrict__ dinv,
                          int* __restrict__ rowptr, int* __restrict__ rowcnt,
                          int* __restrict__ csr_src) {
    __shared__ int cnt[NPER0];
    __shared__ int off[NPER0];
    __shared__ int psum[256];
    const int g = blockIdx.x, t = threadIdx.x;
    const int gnb = g * nper, ebase = g * EPG;

    for (int i = t; i < nper; i += 256) cnt[i] = 0;
    __syncthreads();
    for (int e = t; e < EPG; e += 256) {
        int s = src[ebase + e];
        if (s >= 0) atomicAdd(&cnt[dst[ebase + e] - gnb], 1);
    }
    __syncthreads();
    // exclusive scan of cnt[0..nper)
    const int S = nper >> 8;  // nper/256: 4, 2, or 1
    const int b0 = t * S;
    int loc = 0;
    for (int q = 0; q < S; q++) loc += cnt[b0 + q];
    psum[t] = loc;
    __syncthreads();
    if (t == 0) {
        int run = 0;
        for (int i = 0; i < 256; i++) { int v = psum[i]; psum[i] = run; run += v; }
    }
    __syncthreads();
    int run = psum[t];
    for (int q = 0; q < S; q++) { off[b0 + q] = run; run += cnt[b0 + q]; }
    __syncthreads();
    for (int i = t; i < nper; i += 256) {
        int c = cnt[i];
        float d = (float)c + 1.0f;
        deg[gnb + i] = d;
        dinv[gnb + i] = rsqrtf(d);
        rowptr[gnb + i] = ebase + off[i];
        rowcnt[gnb + i] = c;
    }
    __syncthreads();
    for (int i = t; i < nper; i += 256) cnt[i] = 0;  // reuse as cursor
    __syncthreads();
    for (int e = t; e < EPG; e += 256) {
        int s = src[ebase + e];
        if (s >= 0) {
            int dl = dst[ebase + e] - gnb;
            int p = atomicAdd(&cnt[dl], 1);
            csr_src[ebase + off[dl] + p] = s;
        }
    }
}

// ---------------------------------------------------------------------------
// Per-head projection: h[i, h*32+e] = sum_d x[i, h*32+d] * W[h, d, e].
// Block = 128 threads (one output feature each), 32 nodes per block.
// ---------------------------------------------------------------------------
__global__ void proj_kernel(const float* __restrict__ x, const float* __restrict__ W,
                            float* __restrict__ hp) {
    __shared__ float sW[4096];
    __shared__ float sx[32][128];
    const int t = threadIdx.x;
    const int nb = blockIdx.x * 32;
    for (int i = t; i < 4096; i += 128) sW[i] = W[i];
    for (int i = t; i < 4096; i += 128)
        sx[i >> 7][i & 127] = x[(size_t)(nb + (i >> 7)) * FDIM + (i & 127)];
    __syncthreads();
    const int h = t >> 5, e = t & 31;
    float wcol[32];
#pragma unroll
    for (int d = 0; d < 32; d++) wcol[d] = sW[h * 1024 + d * 32 + e];
    for (int nn = 0; nn < 32; nn++) {
        float acc = 0.0f;
#pragma unroll
        for (int d0 = 0; d0 < 32; d0++) {
            int d = (d0 + h * 8) & 31;  // stagger heads to spread LDS banks
            acc = fmaf(sx[nn][h * 32 + d], wcol[d], acc);
        }
        hp[(size_t)(nb + nn) * FDIM + t] = acc;
    }
}

// ---------------------------------------------------------------------------
// GCN aggregation (gather via CSR) + bias + relu.
// One block per node, 128 threads = features.
// ---------------------------------------------------------------------------
__global__ void agg_kernel(const float* __restrict__ hp, const float* __restrict__ b,
                           const float* __restrict__ dinv, const int* __restrict__ rowptr,
                           const int* __restrict__ rowcnt, const int* __restrict__ csr_src,
                           float* __restrict__ ha) {
    const int i = blockIdx.x;
    const int f = threadIdx.x;
    const float di = dinv[i];
    float acc = hp[(size_t)i * FDIM + f] * di * di;
    const int st = rowptr[i], c = rowcnt[i];
    for (int j = 0; j < c; j++) {
        int s = csr_src[st + j];
        acc = fmaf(hp[(size_t)s * FDIM + f], dinv[s] * di, acc);
    }
    ha[(size_t)i * FDIM + f] = fmaxf(acc + b[f], 0.0f);
}

// ---------------------------------------------------------------------------
// Attention score projection.
// ---------------------------------------------------------------------------
__global__ void attcs_kernel(const float* __restrict__ ha, const float* __restrict__ A,
                             const float* __restrict__ psW, float* __restrict__ cs) {
    const int wid = threadIdx.x >> 6;
    const int lane = threadIdx.x & 63;
    const int i = blockIdx.x * 4 + wid;
    float v0 = ha[(size_t)i * FDIM + lane];
    float v1 = ha[(size_t)i * FDIM + 64 + lane];
    float a0 = v0 * A[lane], p0 = v0 * psW[lane];
    float a1 = v1 * A[64 + lane], p1 = v1 * psW[64 + lane];
    for (int d = 16; d > 0; d >>= 1) {
        a0 += __shfl_down(a0, d, 32);
        p0 += __shfl_down(p0, d, 32);
        a1 += __shfl_down(a1, d, 32);
        p1 += __shfl_down(p1, d, 32);
    }
    float part = a0 * p0 + a1 * p1;  // valid at lanes 0 and 32
    part += __shfl_down(part, 32, 64);
    if (lane == 0) cs[i] = part;
}

// ---------------------------------------------------------------------------
// Fused score-aggregation + per-graph top-k (bitonic sort in LDS).
// ---------------------------------------------------------------------------
__global__ void topk_kernel(const float* __restrict__ cs, const float* __restrict__ dinv,
                            const int* __restrict__ rowptr, const int* __restrict__ rowcnt,
                            const int* __restrict__ csr_src, const float* __restrict__ psb,
                            int nper, int k, int* __restrict__ nmap, int* __restrict__ perm,
                            float* __restrict__ mult) {
    __shared__ float sc[NPER0];
    __shared__ unsigned long long keys[NPER0];
    const int g = blockIdx.x, t = threadIdx.x;
    const int gnb = g * nper;
    const float pb = psb[0];
    for (int i = t; i < nper; i += 256) {
        int node = gnb + i;
        float di = dinv[node];
        float acc = cs[node] * di * di;
        int st = rowptr[node], c = rowcnt[node];
        for (int j = 0; j < c; j++) {
            int s = csr_src[st + j];
            acc = fmaf(cs[s], dinv[s] * di, acc);
        }
        sc[i] = acc + pb;
    }
    __syncthreads();
    for (int i = t; i < nper; i += 256) {
        unsigned u = __float_as_uint(sc[i]);
        u = (u & 0x80000000u) ? ~u : (u | 0x80000000u);  // ascending-sortable
        keys[i] = ((unsigned long long)u << 32) | (unsigned)i;
    }
    for (int ksz = 2; ksz <= nper; ksz <<= 1) {
        for (int j = ksz >> 1; j > 0; j >>= 1) {
            __syncthreads();
            for (int i = t; i < nper; i += 256) {
                int ixj = i ^ j;
                if (ixj > i) {
                    unsigned long long a = keys[i], bb = keys[ixj];
                    bool up = ((i & ksz) == 0);
                    if ((a > bb) == up) { keys[i] = bb; keys[ixj] = a; }
                }
            }
        }
    }
    __syncthreads();
    for (int p = t; p < nper; p += 256) {
        int idx = (int)(keys[p] & 0xFFFFFFFFu);
        int node_old = gnb + idx;
        if (p >= nper - k) {
            int newid = g * k + (p - (nper - k));
            nmap[node_old] = newid;
            perm[newid] = node_old;
            mult[newid] = tanhf(sc[idx]);
        } else {
            nmap[node_old] = -1;
        }
    }
}

// ---------------------------------------------------------------------------
// Pooling gather (xn = h[perm]*tanh(score)) with partial readout.
// Grid: B * (k/PGJ) blocks, 128 threads. Each block handles PGJ kept nodes.
// ---------------------------------------------------------------------------
__global__ void poolgather_kernel(const float* __restrict__ ha, const int* __restrict__ perm,
                                  const float* __restrict__ mult, int k,
                                  float* __restrict__ xn,
                                  float* __restrict__ pmax, float* __restrict__ psum) {
    const int blk = blockIdx.x;
    const int f = threadIdx.x;
    const int base = blk * PGJ;  // global kept-node index base (g*k + c*PGJ)
    float vmax = -1e30f, vsum = 0.0f;
#pragma unroll
    for (int j = 0; j < PGJ; j++) {
        int newid = base + j;
        int old = perm[newid];
        float m = mult[newid];
        float v = ha[(size_t)old * FDIM + f] * m;
        xn[(size_t)newid * FDIM + f] = v;
        vmax = fmaxf(vmax, v);
        vsum += v;
    }
    pmax[(size_t)blk * FDIM + f] = vmax;
    psum[(size_t)blk * FDIM + f] = vsum;
}

// ---------------------------------------------------------------------------
// Reduce partials into per-graph readout r[g, 0:128]=max, r[g,128:256]=mean.
// Grid: B blocks, 128 threads.
// ---------------------------------------------------------------------------
__global__ void readout_reduce(const float* __restrict__ pmax, const float* __restrict__ psum,
                               int nchunks, int k, float* __restrict__ r, int accumulate) {
    const int g = blockIdx.x, f = threadIdx.x;
    float vmax = -1e30f, vsum = 0.0f;
    for (int c = 0; c < nchunks; c++) {
        size_t idx = (size_t)(g * nchunks + c) * FDIM + f;
        vmax = fmaxf(vmax, pmax[idx]);
        vsum += psum[idx];
    }
    float mean = vsum / (float)k;
    if (accumulate) {
        r[g * 256 + f] += vmax;
        r[g * 256 + 128 + f] += mean;
    } else {
        r[g * 256 + f] = vmax;
        r[g * 256 + 128 + f] = mean;
    }
}

// ---------------------------------------------------------------------------
// Edge remap after pooling. Invalid edges carry src = -1 sentinel.
// ---------------------------------------------------------------------------
__global__ void remap_kernel(const int* __restrict__ src, const int* __restrict__ dst,
                             const int* __restrict__ nmap,
                             int* __restrict__ nsrc, int* __restrict__ ndst) {
    const int e = blockIdx.x * 256 + threadIdx.x;
    int so = src[e];
    int ns = (so >= 0) ? nmap[so] : -1;
    int nd = nmap[dst[e]];
    bool valid = (ns >= 0) && (nd >= 0);
    nsrc[e] = valid ? ns : -1;
    ndst[e] = valid ? nd : 0;
}

// ---------------------------------------------------------------------------
// Final MLP + log_softmax. One block per graph, 128 threads.
// ---------------------------------------------------------------------------
__global__ void final_mlp(const float* __restrict__ r,
                          const float* __restrict__ l1W, const float* __restrict__ l1b,
                          const float* __restrict__ l2W, const float* __restrict__ l2b,
                          const float* __restrict__ l3W, const float* __restrict__ l3b,
                          float* __restrict__ out) {
    __shared__ float sz[256], s1[128], s2[64], s3[10], red[2];
    const int g = blockIdx.x, t = threadIdx.x;
    sz[t] = r[g * 256 + t];
    sz[t + 128] = r[g * 256 + 128 + t];
    __syncthreads();
    float acc = l1b[t];
    for (int i = 0; i < 256; i++) acc = fmaf(sz[i], l1W[i * 128 + t], acc);
    s1[t] = fmaxf(acc, 0.0f);
    __syncthreads();
    if (t < 64) {
        float a2 = l2b[t];
        for (int i = 0; i < 128; i++) a2 = fmaf(s1[i], l2W[i * 64 + t], a2);
        s2[t] = fmaxf(a2, 0.0f);
    }
    __syncthreads();
    if (t < 10) {
        float a3 = l3b[t];
        for (int i = 0; i < 64; i++) a3 = fmaf(s2[i], l3W[i * 10 + t], a3);
        s3[t] = a3;
    }
    __syncthreads();
    if (t == 0) {
        float m = -1e30f;
        for (int c = 0; c < 10; c++) m = fmaxf(m, s3[c]);
        float sum = 0.0f;
        for (int c = 0; c < 10; c++) sum += expf(s3[c] - m);
        red[0] = m;
        red[1] = logf(sum);
    }
    __syncthreads();
    if (t < 10) out[g * 10 + t] = s3[t] - red[0] - red[1];
}

// ---------------------------------------------------------------------------
extern "C" void kernel_launch(void* const* d_in, const int* in_sizes, int n_in,
                              void* d_out, int out_size, void* d_ws, size_t ws_size,
                              hipStream_t stream) {
    const float* x    = (const float*)d_in[0];
    const int* src0   = (const int*)d_in[1];
    const int* dst0   = (const int*)d_in[2];
    const float* W1   = (const float*)d_in[3];
    const float* b1   = (const float*)d_in[4];
    const float* A1   = (const float*)d_in[5];
    const float* ps1W = (const float*)d_in[6];
    const float* ps1b = (const float*)d_in[7];
    const float* W2   = (const float*)d_in[8];
    const float* b2   = (const float*)d_in[9];
    const float* A2   = (const float*)d_in[10];
    const float* ps2W = (const float*)d_in[11];
    const float* ps2b = (const float*)d_in[12];
    const float* W3   = (const float*)d_in[13];
    const float* b3   = (const float*)d_in[14];
    const float* A3   = (const float*)d_in[15];
    const float* ps3W = (const float*)d_in[16];
    const float* ps3b = (const float*)d_in[17];
    const float* l1W  = (const float*)d_in[18];
    const float* l1b  = (const float*)d_in[19];
    const float* l2W  = (const float*)d_in[20];
    const float* l2b  = (const float*)d_in[21];
    const float* l3W  = (const float*)d_in[22];
    const float* l3b  = (const float*)d_in[23];
    float* out = (float*)d_out;

    char* ws = (char*)d_ws;
    size_t o = 0;
    auto alloc = [&](size_t bytes) -> void* {
        void* p = ws + o;
        o += (bytes + 255) & ~(size_t)255;
        return p;
    };
    float* hproj   = (float*)alloc((size_t)N0 * FDIM * 4);
    float* hact    = (float*)alloc((size_t)N0 * FDIM * 4);
    float* xn      = (float*)alloc((size_t)N0 * FDIM * 4);
    float* deg     = (float*)alloc(N0 * 4);
    float* dinv    = (float*)alloc(N0 * 4);
    int*   rowptr  = (int*)alloc(N0 * 4);
    int*   rowcnt  = (int*)alloc(N0 * 4);
    int*   csr_src = (int*)alloc(EDG * 4);
    float* cs      = (float*)alloc(N0 * 4);
    int*   nmap    = (int*)alloc(N0 * 4);
    int*   perm    = (int*)alloc(BGR * K1 * 4);
    float* mult    = (float*)alloc(BGR * K1 * 4);
    float* r       = (float*)alloc(BGR * 256 * 4);
    int*   se1     = (int*)alloc(EDG * 4);
    int*   de1     = (int*)alloc(EDG * 4);
    int*   se2     = (int*)alloc(EDG * 4);
    int*   de2     = (int*)alloc(EDG * 4);
    float* pmax    = (float*)alloc((size_t)(BGR * K1 / PGJ) * FDIM * 4);
    float* psum    = (float*)alloc((size_t)(BGR * K1 / PGJ) * FDIM * 4);

    // ---------------- Stage 1: n=32768, nper=1024, k=512 ----------------
    csr_build<<<BGR, 256, 0, stream>>>(src0, dst0, NPER0, deg, dinv, rowptr, rowcnt, csr_src);
    proj_kernel<<<N0 / 32, 128, 0, stream>>>(x, W1, hproj);
    agg_kernel<<<N0, 128, 0, stream>>>(hproj, b1, dinv, rowptr, rowcnt, csr_src, hact);
    attcs_kernel<<<N0 / 4, 256, 0, stream>>>(hact, A1, ps1W, cs);
    topk_kernel<<<BGR, 256, 0, stream>>>(cs, dinv, rowptr, rowcnt, csr_src, ps1b,
                                         NPER0, K1, nmap, perm, mult);
    poolgather_kernel<<<BGR * K1 / PGJ, 128, 0, stream>>>(hact, perm, mult, K1, xn, pmax, psum);
    readout_reduce<<<BGR, 128, 0, stream>>>(pmax, psum, K1 / PGJ, K1, r, 0);
    remap_kernel<<<EDG / 256, 256, 0, stream>>>(src0, dst0, nmap, se1, de1);

    // ---------------- Stage 2: n=16384, nper=512, k=256 ----------------
    const int n1 = BGR * K1;
    csr_build<<<BGR, 256, 0, stream>>>(se1, de1, K1, deg, dinv, rowptr, rowcnt, csr_src);
    proj_kernel<<<n1 / 32, 128, 0, stream>>>(xn, W2, hproj);
    agg_kernel<<<n1, 128, 0, stream>>>(hproj, b2, dinv, rowptr, rowcnt, csr_src, hact);
    attcs_kernel<<<n1 / 4, 256, 0, stream>>>(hact, A2, ps2W, cs);
    topk_kernel<<<BGR, 256, 0, stream>>>(cs, dinv, rowptr, rowcnt, csr_src, ps2b,
                                         K1, K2, nmap, perm, mult);
    poolgather_kernel<<<BGR * K2 / PGJ, 128, 0, stream>>>(hact, perm, mult, K2, xn, pmax, psum);
    readout_reduce<<<BGR, 128, 0, stream>>>(pmax, psum, K2 / PGJ, K2, r, 1);
    remap_kernel<<<EDG / 256, 256, 0, stream>>>(se1, de1, nmap, se2, de2);

    // ---------------- Stage 3: n=8192, nper=256, k=128 ----------------
    const int n2 = BGR * K2;
    csr_build<<<BGR, 256, 0, stream>>>(se2, de2, K2, deg, dinv, rowptr, rowcnt, csr_src);
    proj_kernel<<<n2 / 32, 128, 0, stream>>>(xn, W3, hproj);
    agg_kernel<<<n2, 128, 0, stream>>>(hproj, b3, dinv, rowptr, rowcnt, csr_src, hact);
    attcs_kernel<<<n2 / 4, 256, 0, stream>>>(hact, A3, ps3W, cs);
    topk_kernel<<<BGR, 256, 0, stream>>>(cs, dinv, rowptr, rowcnt, csr_src, ps3b,
                                         K2, K3, nmap, perm, mult);
    poolgather_kernel<<<BGR * K3 / PGJ, 128, 0, stream>>>(hact, perm, mult, K3, xn, pmax, psum);
    readout_reduce<<<BGR, 128, 0, stream>>>(pmax, psum, K3 / PGJ, K3, r, 1);

    // ---------------- Final MLP ----------------
    final_mlp<<<BGR, 128, 0, stream>>>(r, l1W, l1b, l2W, l2b, l3W, l3b, out);

    (void)in_sizes; (void)n_in; (void)out_size; (void)ws_size;
}

// Round 3
// 498.172 us; speedup vs baseline: 1.5579x; 1.2190x over previous
//
#include <hip/hip_runtime.h>
#include <math.h>

#define BGR 32
#define NPER0 1024
#define N0 (BGR * NPER0)
#define FDIM 128
#define EDG 524288
#define EPG (EDG / BGR)
#define K1 512
#define K2 256
#define K3 128
#define PGJ 8  // kept nodes per poolgather block

// ---------------------------------------------------------------------------
// Parallel CSR build: zero -> count (atomic, 1 thread/edge) -> per-graph scan
// -> scatter (atomic cursor, 1 thread/edge). Edge validity = (src[e] >= 0).
// ---------------------------------------------------------------------------
__global__ void zero_int(int* __restrict__ p, int n) {
    int i = blockIdx.x * 256 + threadIdx.x;
    if (i < n) p[i] = 0;
}

__global__ void count_kernel(const int* __restrict__ src, const int* __restrict__ dst,
                             int* __restrict__ cnt) {
    int e = blockIdx.x * 256 + threadIdx.x;
    int s = src[e];
    if (s >= 0) atomicAdd(&cnt[dst[e]], 1);
}

// Per-graph exclusive scan of cnt -> rowptr; writes dinv/rowcnt; zeroes cnt
// (reused as scatter cursor). 32 blocks x 256 threads over nper<=1024 elems.
__global__ void scan_kernel(int* __restrict__ cnt, int nper,
                            float* __restrict__ dinv,
                            int* __restrict__ rowptr, int* __restrict__ rowcnt) {
    __shared__ int scnt[NPER0];
    __shared__ int soff[NPER0];
    __shared__ int psum[256];
    const int g = blockIdx.x, t = threadIdx.x;
    const int gnb = g * nper, ebase = g * EPG;
    for (int i = t; i < nper; i += 256) scnt[i] = cnt[gnb + i];
    __syncthreads();
    const int S = nper >> 8;  // 4, 2, or 1
    const int b0 = t * S;
    int loc = 0;
    for (int q = 0; q < S; q++) loc += scnt[b0 + q];
    psum[t] = loc;
    __syncthreads();
    if (t == 0) {
        int run = 0;
        for (int i = 0; i < 256; i++) { int v = psum[i]; psum[i] = run; run += v; }
    }
    __syncthreads();
    int run = psum[t];
    for (int q = 0; q < S; q++) { soff[b0 + q] = run; run += scnt[b0 + q]; }
    __syncthreads();
    for (int i = t; i < nper; i += 256) {
        int c = scnt[i];
        dinv[gnb + i] = rsqrtf((float)c + 1.0f);
        rowptr[gnb + i] = ebase + soff[i];
        rowcnt[gnb + i] = c;
        cnt[gnb + i] = 0;  // cursor for scatter
    }
}

__global__ void scatter_kernel(const int* __restrict__ src, const int* __restrict__ dst,
                               const int* __restrict__ rowptr, int* __restrict__ cursor,
                               int* __restrict__ csr_src) {
    int e = blockIdx.x * 256 + threadIdx.x;
    int s = src[e];
    if (s >= 0) {
        int d = dst[e];
        int p = atomicAdd(&cursor[d], 1);
        csr_src[rowptr[d] + p] = s;
    }
}

// ---------------------------------------------------------------------------
// Per-head projection: h[i, h*32+e] = sum_d x[i, h*32+d] * W[h, d, e].
// Block = 128 threads (one output feature each), 32 nodes per block.
// ---------------------------------------------------------------------------
__global__ void proj_kernel(const float* __restrict__ x, const float* __restrict__ W,
                            float* __restrict__ hp) {
    __shared__ float sW[4096];
    __shared__ float sx[32][128];
    const int t = threadIdx.x;
    const int nb = blockIdx.x * 32;
    for (int i = t; i < 4096; i += 128) sW[i] = W[i];
    for (int i = t; i < 4096; i += 128)
        sx[i >> 7][i & 127] = x[(size_t)(nb + (i >> 7)) * FDIM + (i & 127)];
    __syncthreads();
    const int h = t >> 5, e = t & 31;
    float wcol[32];
#pragma unroll
    for (int d = 0; d < 32; d++) wcol[d] = sW[h * 1024 + d * 32 + e];
    for (int nn = 0; nn < 32; nn++) {
        float acc = 0.0f;
#pragma unroll
        for (int d0 = 0; d0 < 32; d0++) {
            int d = (d0 + h * 8) & 31;  // stagger heads to spread LDS banks
            acc = fmaf(sx[nn][h * 32 + d], wcol[d], acc);
        }
        hp[(size_t)(nb + nn) * FDIM + t] = acc;
    }
}

// ---------------------------------------------------------------------------
// GCN aggregation (gather via CSR) + bias + relu.
// One block per node, 128 threads = features.
// ---------------------------------------------------------------------------
__global__ void agg_kernel(const float* __restrict__ hp, const float* __restrict__ b,
                           const float* __restrict__ dinv, const int* __restrict__ rowptr,
                           const int* __restrict__ rowcnt, const int* __restrict__ csr_src,
                           float* __restrict__ ha) {
    const int i = blockIdx.x;
    const int f = threadIdx.x;
    const float di = dinv[i];
    float acc = hp[(size_t)i * FDIM + f] * di * di;
    const int st = rowptr[i], c = rowcnt[i];
    for (int j = 0; j < c; j++) {
        int s = csr_src[st + j];
        acc = fmaf(hp[(size_t)s * FDIM + f], dinv[s] * di, acc);
    }
    ha[(size_t)i * FDIM + f] = fmaxf(acc + b[f], 0.0f);
}

// ---------------------------------------------------------------------------
// Attention score projection.
// ---------------------------------------------------------------------------
__global__ void attcs_kernel(const float* __restrict__ ha, const float* __restrict__ A,
                             const float* __restrict__ psW, float* __restrict__ cs) {
    const int wid = threadIdx.x >> 6;
    const int lane = threadIdx.x & 63;
    const int i = blockIdx.x * 4 + wid;
    float v0 = ha[(size_t)i * FDIM + lane];
    float v1 = ha[(size_t)i * FDIM + 64 + lane];
    float a0 = v0 * A[lane], p0 = v0 * psW[lane];
    float a1 = v1 * A[64 + lane], p1 = v1 * psW[64 + lane];
    for (int d = 16; d > 0; d >>= 1) {
        a0 += __shfl_down(a0, d, 32);
        p0 += __shfl_down(p0, d, 32);
        a1 += __shfl_down(a1, d, 32);
        p1 += __shfl_down(p1, d, 32);
    }
    float part = a0 * p0 + a1 * p1;  // valid at lanes 0 and 32
    part += __shfl_down(part, 32, 64);
    if (lane == 0) cs[i] = part;
}

// ---------------------------------------------------------------------------
// Fused score-aggregation + per-graph top-k (bitonic sort in LDS).
// ---------------------------------------------------------------------------
__global__ void topk_kernel(const float* __restrict__ cs, const float* __restrict__ dinv,
                            const int* __restrict__ rowptr, const int* __restrict__ rowcnt,
                            const int* __restrict__ csr_src, const float* __restrict__ psb,
                            int nper, int k, int* __restrict__ nmap, int* __restrict__ perm,
                            float* __restrict__ mult) {
    __shared__ float sc[NPER0];
    __shared__ unsigned long long keys[NPER0];
    const int g = blockIdx.x, t = threadIdx.x;
    const int gnb = g * nper;
    const float pb = psb[0];
    for (int i = t; i < nper; i += 256) {
        int node = gnb + i;
        float di = dinv[node];
        float acc = cs[node] * di * di;
        int st = rowptr[node], c = rowcnt[node];
        for (int j = 0; j < c; j++) {
            int s = csr_src[st + j];
            acc = fmaf(cs[s], dinv[s] * di, acc);
        }
        sc[i] = acc + pb;
    }
    __syncthreads();
    for (int i = t; i < nper; i += 256) {
        unsigned u = __float_as_uint(sc[i]);
        u = (u & 0x80000000u) ? ~u : (u | 0x80000000u);  // ascending-sortable
        keys[i] = ((unsigned long long)u << 32) | (unsigned)i;
    }
    for (int ksz = 2; ksz <= nper; ksz <<= 1) {
        for (int j = ksz >> 1; j > 0; j >>= 1) {
            __syncthreads();
            for (int i = t; i < nper; i += 256) {
                int ixj = i ^ j;
                if (ixj > i) {
                    unsigned long long a = keys[i], bb = keys[ixj];
                    bool up = ((i & ksz) == 0);
                    if ((a > bb) == up) { keys[i] = bb; keys[ixj] = a; }
                }
            }
        }
    }
    __syncthreads();
    for (int p = t; p < nper; p += 256) {
        int idx = (int)(keys[p] & 0xFFFFFFFFu);
        int node_old = gnb + idx;
        if (p >= nper - k) {
            int newid = g * k + (p - (nper - k));
            nmap[node_old] = newid;
            perm[newid] = node_old;
            mult[newid] = tanhf(sc[idx]);
        } else {
            nmap[node_old] = -1;
        }
    }
}

// ---------------------------------------------------------------------------
// Pooling gather (xn = h[perm]*tanh(score)) with partial readout.
// Grid: B * (k/PGJ) blocks, 128 threads. Each block handles PGJ kept nodes.
// ---------------------------------------------------------------------------
__global__ void poolgather_kernel(const float* __restrict__ ha, const int* __restrict__ perm,
                                  const float* __restrict__ mult, int k,
                                  float* __restrict__ xn,
                                  float* __restrict__ pmax, float* __restrict__ psum) {
    const int blk = blockIdx.x;
    const int f = threadIdx.x;
    const int base = blk * PGJ;  // global kept-node index base (g*k + c*PGJ)
    float vmax = -1e30f, vsum = 0.0f;
#pragma unroll
    for (int j = 0; j < PGJ; j++) {
        int newid = base + j;
        int old = perm[newid];
        float m = mult[newid];
        float v = ha[(size_t)old * FDIM + f] * m;
        xn[(size_t)newid * FDIM + f] = v;
        vmax = fmaxf(vmax, v);
        vsum += v;
    }
    pmax[(size_t)blk * FDIM + f] = vmax;
    psum[(size_t)blk * FDIM + f] = vsum;
}

// ---------------------------------------------------------------------------
// Reduce partials into per-graph readout r[g, 0:128]=max, r[g,128:256]=mean.
// ---------------------------------------------------------------------------
__global__ void readout_reduce(const float* __restrict__ pmax, const float* __restrict__ psum,
                               int nchunks, int k, float* __restrict__ r, int accumulate) {
    const int g = blockIdx.x, f = threadIdx.x;
    float vmax = -1e30f, vsum = 0.0f;
    for (int c = 0; c < nchunks; c++) {
        size_t idx = (size_t)(g * nchunks + c) * FDIM + f;
        vmax = fmaxf(vmax, pmax[idx]);
        vsum += psum[idx];
    }
    float mean = vsum / (float)k;
    if (accumulate) {
        r[g * 256 + f] += vmax;
        r[g * 256 + 128 + f] += mean;
    } else {
        r[g * 256 + f] = vmax;
        r[g * 256 + 128 + f] = mean;
    }
}

// ---------------------------------------------------------------------------
// Edge remap after pooling, fused with next stage's degree count.
// Invalid edges carry src = -1 sentinel. cnt must be zeroed beforehand.
// ---------------------------------------------------------------------------
__global__ void remap_kernel(const int* __restrict__ src, const int* __restrict__ dst,
                             const int* __restrict__ nmap,
                             int* __restrict__ nsrc, int* __restrict__ ndst,
                             int* __restrict__ cnt) {
    const int e = blockIdx.x * 256 + threadIdx.x;
    int so = src[e];
    int ns = (so >= 0) ? nmap[so] : -1;
    int nd = nmap[dst[e]];
    bool valid = (ns >= 0) && (nd >= 0);
    nsrc[e] = valid ? ns : -1;
    ndst[e] = valid ? nd : 0;
    if (valid) atomicAdd(&cnt[nd], 1);
}

// ---------------------------------------------------------------------------
// Final MLP + log_softmax. One block per graph, 128 threads.
// ---------------------------------------------------------------------------
__global__ void final_mlp(const float* __restrict__ r,
                          const float* __restrict__ l1W, const float* __restrict__ l1b,
                          const float* __restrict__ l2W, const float* __restrict__ l2b,
                          const float* __restrict__ l3W, const float* __restrict__ l3b,
                          float* __restrict__ out) {
    __shared__ float sz[256], s1[128], s2[64], s3[10], red[2];
    const int g = blockIdx.x, t = threadIdx.x;
    sz[t] = r[g * 256 + t];
    sz[t + 128] = r[g * 256 + 128 + t];
    __syncthreads();
    float acc = l1b[t];
    for (int i = 0; i < 256; i++) acc = fmaf(sz[i], l1W[i * 128 + t], acc);
    s1[t] = fmaxf(acc, 0.0f);
    __syncthreads();
    if (t < 64) {
        float a2 = l2b[t];
        for (int i = 0; i < 128; i++) a2 = fmaf(s1[i], l2W[i * 64 + t], a2);
        s2[t] = fmaxf(a2, 0.0f);
    }
    __syncthreads();
    if (t < 10) {
        float a3 = l3b[t];
        for (int i = 0; i < 64; i++) a3 = fmaf(s2[i], l3W[i * 10 + t], a3);
        s3[t] = a3;
    }
    __syncthreads();
    if (t == 0) {
        float m = -1e30f;
        for (int c = 0; c < 10; c++) m = fmaxf(m, s3[c]);
        float sum = 0.0f;
        for (int c = 0; c < 10; c++) sum += expf(s3[c] - m);
        red[0] = m;
        red[1] = logf(sum);
    }
    __syncthreads();
    if (t < 10) out[g * 10 + t] = s3[t] - red[0] - red[1];
}

// ---------------------------------------------------------------------------
extern "C" void kernel_launch(void* const* d_in, const int* in_sizes, int n_in,
                              void* d_out, int out_size, void* d_ws, size_t ws_size,
                              hipStream_t stream) {
    const float* x    = (const float*)d_in[0];
    const int* src0   = (const int*)d_in[1];
    const int* dst0   = (const int*)d_in[2];
    const float* W1   = (const float*)d_in[3];
    const float* b1   = (const float*)d_in[4];
    const float* A1   = (const float*)d_in[5];
    const float* ps1W = (const float*)d_in[6];
    const float* ps1b = (const float*)d_in[7];
    const float* W2   = (const float*)d_in[8];
    const float* b2   = (const float*)d_in[9];
    const float* A2   = (const float*)d_in[10];
    const float* ps2W = (const float*)d_in[11];
    const float* ps2b = (const float*)d_in[12];
    const float* W3   = (const float*)d_in[13];
    const float* b3   = (const float*)d_in[14];
    const float* A3   = (const float*)d_in[15];
    const float* ps3W = (const float*)d_in[16];
    const float* ps3b = (const float*)d_in[17];
    const float* l1W  = (const float*)d_in[18];
    const float* l1b  = (const float*)d_in[19];
    const float* l2W  = (const float*)d_in[20];
    const float* l2b  = (const float*)d_in[21];
    const float* l3W  = (const float*)d_in[22];
    const float* l3b  = (const float*)d_in[23];
    float* out = (float*)d_out;

    char* ws = (char*)d_ws;
    size_t o = 0;
    auto alloc = [&](size_t bytes) -> void* {
        void* p = ws + o;
        o += (bytes + 255) & ~(size_t)255;
        return p;
    };
    float* hproj   = (float*)alloc((size_t)N0 * FDIM * 4);
    float* hact    = (float*)alloc((size_t)N0 * FDIM * 4);
    float* xn      = (float*)alloc((size_t)N0 * FDIM * 4);
    int*   cnt     = (int*)alloc(N0 * 4);
    float* dinv    = (float*)alloc(N0 * 4);
    int*   rowptr  = (int*)alloc(N0 * 4);
    int*   rowcnt  = (int*)alloc(N0 * 4);
    int*   csr_src = (int*)alloc(EDG * 4);
    float* cs      = (float*)alloc(N0 * 4);
    int*   nmap    = (int*)alloc(N0 * 4);
    int*   perm    = (int*)alloc(BGR * K1 * 4);
    float* mult    = (float*)alloc(BGR * K1 * 4);
    float* r       = (float*)alloc(BGR * 256 * 4);
    int*   se1     = (int*)alloc(EDG * 4);
    int*   de1     = (int*)alloc(EDG * 4);
    int*   se2     = (int*)alloc(EDG * 4);
    int*   de2     = (int*)alloc(EDG * 4);
    float* pmax    = (float*)alloc((size_t)(BGR * K1 / PGJ) * FDIM * 4);
    float* psum    = (float*)alloc((size_t)(BGR * K1 / PGJ) * FDIM * 4);

    // ---------------- Stage 1: n=32768, nper=1024, k=512 ----------------
    zero_int<<<N0 / 256, 256, 0, stream>>>(cnt, N0);
    count_kernel<<<EDG / 256, 256, 0, stream>>>(src0, dst0, cnt);
    scan_kernel<<<BGR, 256, 0, stream>>>(cnt, NPER0, dinv, rowptr, rowcnt);
    scatter_kernel<<<EDG / 256, 256, 0, stream>>>(src0, dst0, rowptr, cnt, csr_src);
    proj_kernel<<<N0 / 32, 128, 0, stream>>>(x, W1, hproj);
    agg_kernel<<<N0, 128, 0, stream>>>(hproj, b1, dinv, rowptr, rowcnt, csr_src, hact);
    attcs_kernel<<<N0 / 4, 256, 0, stream>>>(hact, A1, ps1W, cs);
    topk_kernel<<<BGR, 256, 0, stream>>>(cs, dinv, rowptr, rowcnt, csr_src, ps1b,
                                         NPER0, K1, nmap, perm, mult);
    poolgather_kernel<<<BGR * K1 / PGJ, 128, 0, stream>>>(hact, perm, mult, K1, xn, pmax, psum);
    readout_reduce<<<BGR, 128, 0, stream>>>(pmax, psum, K1 / PGJ, K1, r, 0);

    // ---------------- Stage 2: n=16384, nper=512, k=256 ----------------
    const int n1 = BGR * K1;
    zero_int<<<(n1 + 255) / 256, 256, 0, stream>>>(cnt, n1);
    remap_kernel<<<EDG / 256, 256, 0, stream>>>(src0, dst0, nmap, se1, de1, cnt);
    scan_kernel<<<BGR, 256, 0, stream>>>(cnt, K1, dinv, rowptr, rowcnt);
    scatter_kernel<<<EDG / 256, 256, 0, stream>>>(se1, de1, rowptr, cnt, csr_src);
    proj_kernel<<<n1 / 32, 128, 0, stream>>>(xn, W2, hproj);
    agg_kernel<<<n1, 128, 0, stream>>>(hproj, b2, dinv, rowptr, rowcnt, csr_src, hact);
    attcs_kernel<<<n1 / 4, 256, 0, stream>>>(hact, A2, ps2W, cs);
    topk_kernel<<<BGR, 256, 0, stream>>>(cs, dinv, rowptr, rowcnt, csr_src, ps2b,
                                         K1, K2, nmap, perm, mult);
    poolgather_kernel<<<BGR * K2 / PGJ, 128, 0, stream>>>(hact, perm, mult, K2, xn, pmax, psum);
    readout_reduce<<<BGR, 128, 0, stream>>>(pmax, psum, K2 / PGJ, K2, r, 1);

    // ---------------- Stage 3: n=8192, nper=256, k=128 ----------------
    const int n2 = BGR * K2;
    zero_int<<<(n2 + 255) / 256, 256, 0, stream>>>(cnt, n2);
    remap_kernel<<<EDG / 256, 256, 0, stream>>>(se1, de1, nmap, se2, de2, cnt);
    scan_kernel<<<BGR, 256, 0, stream>>>(cnt, K2, dinv, rowptr, rowcnt);
    scatter_kernel<<<EDG / 256, 256, 0, stream>>>(se2, de2, rowptr, cnt, csr_src);
    proj_kernel<<<n2 / 32, 128, 0, stream>>>(xn, W3, hproj);
    agg_kernel<<<n2, 128, 0, stream>>>(hproj, b3, dinv, rowptr, rowcnt, csr_src, hact);
    attcs_kernel<<<n2 / 4, 256, 0, stream>>>(hact, A3, ps3W, cs);
    topk_kernel<<<BGR, 256, 0, stream>>>(cs, dinv, rowptr, rowcnt, csr_src, ps3b,
                                         K2, K3, nmap, perm, mult);
    poolgather_kernel<<<BGR * K3 / PGJ, 128, 0, stream>>>(hact, perm, mult, K3, xn, pmax, psum);
    readout_reduce<<<BGR, 128, 0, stream>>>(pmax, psum, K3 / PGJ, K3, r, 1);

    // ---------------- Final MLP ----------------
    final_mlp<<<BGR, 128, 0, stream>>>(r, l1W, l1b, l2W, l2b, l3W, l3b, out);

    (void)in_sizes; (void)n_in; (void)out_size; (void)ws_size;
}

// Round 4
// 449.365 us; speedup vs baseline: 1.7271x; 1.1086x over previous
//
#include <hip/hip_runtime.h>
#include <math.h>

#define BGR 32
#define NPER0 1024
#define N0 (BGR * NPER0)
#define FDIM 128
#define EDG 524288
#define EPG (EDG / BGR)
#define K1 512
#define K2 256
#define K3 128
#define PGJ 8  // kept nodes per poolgather block

// ---------------------------------------------------------------------------
// Parallel CSR build: zero -> count (atomic, 1 thread/edge) -> per-graph scan
// -> scatter (atomic cursor, 1 thread/edge). Edge validity = (src[e] >= 0).
// ---------------------------------------------------------------------------
__global__ void zero_int(int* __restrict__ p, int n) {
    int i = blockIdx.x * 256 + threadIdx.x;
    if (i < n) p[i] = 0;
}

__global__ void count_kernel(const int* __restrict__ src, const int* __restrict__ dst,
                             int* __restrict__ cnt) {
    int e = blockIdx.x * 256 + threadIdx.x;
    int s = src[e];
    if (s >= 0) atomicAdd(&cnt[dst[e]], 1);
}

// Per-graph exclusive scan of cnt -> rowptr; writes dinv/rowcnt; zeroes cnt
// (reused as scatter cursor). 32 blocks x 256 threads over nper<=1024 elems.
__global__ void scan_kernel(int* __restrict__ cnt, int nper,
                            float* __restrict__ dinv,
                            int* __restrict__ rowptr, int* __restrict__ rowcnt) {
    __shared__ int scnt[NPER0];
    __shared__ int soff[NPER0];
    __shared__ int psum[256];
    const int g = blockIdx.x, t = threadIdx.x;
    const int gnb = g * nper, ebase = g * EPG;
    for (int i = t; i < nper; i += 256) scnt[i] = cnt[gnb + i];
    __syncthreads();
    const int S = nper >> 8;  // 4, 2, or 1
    const int b0 = t * S;
    int loc = 0;
    for (int q = 0; q < S; q++) loc += scnt[b0 + q];
    psum[t] = loc;
    __syncthreads();
    if (t == 0) {
        int run = 0;
        for (int i = 0; i < 256; i++) { int v = psum[i]; psum[i] = run; run += v; }
    }
    __syncthreads();
    int run = psum[t];
    for (int q = 0; q < S; q++) { soff[b0 + q] = run; run += scnt[b0 + q]; }
    __syncthreads();
    for (int i = t; i < nper; i += 256) {
        int c = scnt[i];
        dinv[gnb + i] = rsqrtf((float)c + 1.0f);
        rowptr[gnb + i] = ebase + soff[i];
        rowcnt[gnb + i] = c;
        cnt[gnb + i] = 0;  // cursor for scatter
    }
}

__global__ void scatter_kernel(const int* __restrict__ src, const int* __restrict__ dst,
                               const int* __restrict__ rowptr, int* __restrict__ cursor,
                               int* __restrict__ csr_src) {
    int e = blockIdx.x * 256 + threadIdx.x;
    int s = src[e];
    if (s >= 0) {
        int d = dst[e];
        int p = atomicAdd(&cursor[d], 1);
        csr_src[rowptr[d] + p] = s;
    }
}

// ---------------------------------------------------------------------------
// Per-head projection: h[i, h*32+e] = sum_d x[i, h*32+d] * W[h, d, e].
// Block = 128 threads (one output feature each), 32 nodes per block.
// ---------------------------------------------------------------------------
__global__ void proj_kernel(const float* __restrict__ x, const float* __restrict__ W,
                            float* __restrict__ hp) {
    __shared__ float sW[4096];
    __shared__ float sx[32][128];
    const int t = threadIdx.x;
    const int nb = blockIdx.x * 32;
    for (int i = t; i < 4096; i += 128) sW[i] = W[i];
    for (int i = t; i < 4096; i += 128)
        sx[i >> 7][i & 127] = x[(size_t)(nb + (i >> 7)) * FDIM + (i & 127)];
    __syncthreads();
    const int h = t >> 5, e = t & 31;
    float wcol[32];
#pragma unroll
    for (int d = 0; d < 32; d++) wcol[d] = sW[h * 1024 + d * 32 + e];
    for (int nn = 0; nn < 32; nn++) {
        float acc = 0.0f;
#pragma unroll
        for (int d0 = 0; d0 < 32; d0++) {
            int d = (d0 + h * 8) & 31;  // stagger heads to spread LDS banks
            acc = fmaf(sx[nn][h * 32 + d], wcol[d], acc);
        }
        hp[(size_t)(nb + nn) * FDIM + t] = acc;
    }
}

// ---------------------------------------------------------------------------
// GCN aggregation (gather via CSR) + bias + relu.
// One WAVE per node (loop count wave-uniform, no divergence); lane covers 2
// features (float2, 512B/row). Edge indices + dinv are prefetched 64-wide and
// broadcast via shfl so neighbor-row gathers are independent (4x unrolled).
// Graph->XCD swizzle: blockIdx%32 = graph, so graph g lands on XCD g%8 and
// its 512KB feature slice stays L2-resident.
// ---------------------------------------------------------------------------
__global__ void agg_kernel(const float* __restrict__ hp, const float* __restrict__ b,
                           const float* __restrict__ dinv, const int* __restrict__ rowptr,
                           const int* __restrict__ rowcnt, const int* __restrict__ csr_src,
                           float* __restrict__ ha, int nper) {
    const int w = threadIdx.x >> 6;
    const int lane = threadIdx.x & 63;
    const int g = blockIdx.x & 31;
    const int chunk = blockIdx.x >> 5;
    const int i = g * nper + chunk * 4 + w;
    const float di = dinv[i];
    const float2* __restrict__ hp2 = (const float2*)hp;
    float2 self = hp2[(size_t)i * 64 + lane];
    float accx = self.x * di * di, accy = self.y * di * di;
    const int st = rowptr[i];
    const int c = rowcnt[i];
    for (int base = 0; base < c; base += 64) {
        const int cc = min(64, c - base);
        int idx = 0;
        float dv = 0.0f;
        if (lane < cc) {
            idx = csr_src[st + base + lane];
            dv = dinv[idx];
        }
        int j = 0;
        for (; j + 3 < cc; j += 4) {
            int s0 = __shfl(idx, j, 64);
            int s1 = __shfl(idx, j + 1, 64);
            int s2 = __shfl(idx, j + 2, 64);
            int s3 = __shfl(idx, j + 3, 64);
            float c0 = __shfl(dv, j, 64) * di;
            float c1 = __shfl(dv, j + 1, 64) * di;
            float c2 = __shfl(dv, j + 2, 64) * di;
            float c3 = __shfl(dv, j + 3, 64) * di;
            float2 v0 = hp2[(size_t)s0 * 64 + lane];
            float2 v1 = hp2[(size_t)s1 * 64 + lane];
            float2 v2 = hp2[(size_t)s2 * 64 + lane];
            float2 v3 = hp2[(size_t)s3 * 64 + lane];
            accx = fmaf(v0.x, c0, accx); accy = fmaf(v0.y, c0, accy);
            accx = fmaf(v1.x, c1, accx); accy = fmaf(v1.y, c1, accy);
            accx = fmaf(v2.x, c2, accx); accy = fmaf(v2.y, c2, accy);
            accx = fmaf(v3.x, c3, accx); accy = fmaf(v3.y, c3, accy);
        }
        for (; j < cc; j++) {
            int s = __shfl(idx, j, 64);
            float co = __shfl(dv, j, 64) * di;
            float2 v = hp2[(size_t)s * 64 + lane];
            accx = fmaf(v.x, co, accx); accy = fmaf(v.y, co, accy);
        }
    }
    float2 bb = ((const float2*)b)[lane];
    float2 o;
    o.x = fmaxf(accx + bb.x, 0.0f);
    o.y = fmaxf(accy + bb.y, 0.0f);
    ((float2*)ha)[(size_t)i * 64 + lane] = o;
}

// ---------------------------------------------------------------------------
// Attention score projection (float2, segmented head reductions).
// cs[i] = sum_h (x_h . A_h) * (x_h . psW_h); head h = lanes [16h,16h+16).
// ---------------------------------------------------------------------------
__global__ void attcs_kernel(const float* __restrict__ ha, const float* __restrict__ A,
                             const float* __restrict__ psW, float* __restrict__ cs) {
    const int wid = threadIdx.x >> 6;
    const int lane = threadIdx.x & 63;
    const int i = blockIdx.x * 4 + wid;
    float2 v = ((const float2*)ha)[(size_t)i * 64 + lane];
    float2 Av = ((const float2*)A)[lane];
    float2 Pv = ((const float2*)psW)[lane];
    float a = v.x * Av.x + v.y * Av.y;
    float p = v.x * Pv.x + v.y * Pv.y;
    for (int d = 8; d > 0; d >>= 1) {
        a += __shfl_down(a, d, 16);
        p += __shfl_down(p, d, 16);
    }
    float part = a * p;                  // heads at lanes 0,16,32,48
    part += __shfl_down(part, 16, 64);   // lane0+=lane16, lane32+=lane48
    part += __shfl_down(part, 32, 64);   // lane0+=lane32
    if (lane == 0) cs[i] = part;
}

// ---------------------------------------------------------------------------
// Fused score-aggregation + per-graph top-k (bitonic sort in LDS).
// ---------------------------------------------------------------------------
__global__ void topk_kernel(const float* __restrict__ cs, const float* __restrict__ dinv,
                            const int* __restrict__ rowptr, const int* __restrict__ rowcnt,
                            const int* __restrict__ csr_src, const float* __restrict__ psb,
                            int nper, int k, int* __restrict__ nmap, int* __restrict__ perm,
                            float* __restrict__ mult) {
    __shared__ float sc[NPER0];
    __shared__ unsigned long long keys[NPER0];
    const int g = blockIdx.x, t = threadIdx.x;
    const int gnb = g * nper;
    const float pb = psb[0];
    for (int i = t; i < nper; i += 256) {
        int node = gnb + i;
        float di = dinv[node];
        float acc = cs[node] * di * di;
        int st = rowptr[node], c = rowcnt[node];
        for (int j = 0; j < c; j++) {
            int s = csr_src[st + j];
            acc = fmaf(cs[s], dinv[s] * di, acc);
        }
        sc[i] = acc + pb;
    }
    __syncthreads();
    for (int i = t; i < nper; i += 256) {
        unsigned u = __float_as_uint(sc[i]);
        u = (u & 0x80000000u) ? ~u : (u | 0x80000000u);  // ascending-sortable
        keys[i] = ((unsigned long long)u << 32) | (unsigned)i;
    }
    for (int ksz = 2; ksz <= nper; ksz <<= 1) {
        for (int j = ksz >> 1; j > 0; j >>= 1) {
            __syncthreads();
            for (int i = t; i < nper; i += 256) {
                int ixj = i ^ j;
                if (ixj > i) {
                    unsigned long long a = keys[i], bb = keys[ixj];
                    bool up = ((i & ksz) == 0);
                    if ((a > bb) == up) { keys[i] = bb; keys[ixj] = a; }
                }
            }
        }
    }
    __syncthreads();
    for (int p = t; p < nper; p += 256) {
        int idx = (int)(keys[p] & 0xFFFFFFFFu);
        int node_old = gnb + idx;
        if (p >= nper - k) {
            int newid = g * k + (p - (nper - k));
            nmap[node_old] = newid;
            perm[newid] = node_old;
            mult[newid] = tanhf(sc[idx]);
        } else {
            nmap[node_old] = -1;
        }
    }
}

// ---------------------------------------------------------------------------
// Pooling gather (xn = h[perm]*tanh(score)) with partial readout.
// Grid: B*(k/PGJ) blocks, 128 threads; graph-swizzled (blk%32 = graph).
// ---------------------------------------------------------------------------
__global__ void poolgather_kernel(const float* __restrict__ ha, const int* __restrict__ perm,
                                  const float* __restrict__ mult, int k,
                                  float* __restrict__ xn,
                                  float* __restrict__ pmax, float* __restrict__ psum) {
    const int g = blockIdx.x & 31;
    const int c = blockIdx.x >> 5;
    const int f = threadIdx.x;
    const int base = g * k + c * PGJ;
    float vmax = -1e30f, vsum = 0.0f;
#pragma unroll
    for (int j = 0; j < PGJ; j++) {
        int newid = base + j;
        int old = perm[newid];
        float m = mult[newid];
        float v = ha[(size_t)old * FDIM + f] * m;
        xn[(size_t)newid * FDIM + f] = v;
        vmax = fmaxf(vmax, v);
        vsum += v;
    }
    const int pidx = g * (k / PGJ) + c;
    pmax[(size_t)pidx * FDIM + f] = vmax;
    psum[(size_t)pidx * FDIM + f] = vsum;
}

// ---------------------------------------------------------------------------
// Reduce partials into per-graph readout r[g, 0:128]=max, r[g,128:256]=mean.
// ---------------------------------------------------------------------------
__global__ void readout_reduce(const float* __restrict__ pmax, const float* __restrict__ psum,
                               int nchunks, int k, float* __restrict__ r, int accumulate) {
    const int g = blockIdx.x, f = threadIdx.x;
    float vmax = -1e30f, vsum = 0.0f;
    for (int c = 0; c < nchunks; c++) {
        size_t idx = (size_t)(g * nchunks + c) * FDIM + f;
        vmax = fmaxf(vmax, pmax[idx]);
        vsum += psum[idx];
    }
    float mean = vsum / (float)k;
    if (accumulate) {
        r[g * 256 + f] += vmax;
        r[g * 256 + 128 + f] += mean;
    } else {
        r[g * 256 + f] = vmax;
        r[g * 256 + 128 + f] = mean;
    }
}

// ---------------------------------------------------------------------------
// Edge remap after pooling, fused with next stage's degree count.
// Invalid edges carry src = -1 sentinel. cnt must be zeroed beforehand.
// ---------------------------------------------------------------------------
__global__ void remap_kernel(const int* __restrict__ src, const int* __restrict__ dst,
                             const int* __restrict__ nmap,
                             int* __restrict__ nsrc, int* __restrict__ ndst,
                             int* __restrict__ cnt) {
    const int e = blockIdx.x * 256 + threadIdx.x;
    int so = src[e];
    int ns = (so >= 0) ? nmap[so] : -1;
    int nd = nmap[dst[e]];
    bool valid = (ns >= 0) && (nd >= 0);
    nsrc[e] = valid ? ns : -1;
    ndst[e] = valid ? nd : 0;
    if (valid) atomicAdd(&cnt[nd], 1);
}

// ---------------------------------------------------------------------------
// Final MLP + log_softmax. One block per graph, 128 threads.
// ---------------------------------------------------------------------------
__global__ void final_mlp(const float* __restrict__ r,
                          const float* __restrict__ l1W, const float* __restrict__ l1b,
                          const float* __restrict__ l2W, const float* __restrict__ l2b,
                          const float* __restrict__ l3W, const float* __restrict__ l3b,
                          float* __restrict__ out) {
    __shared__ float sz[256], s1[128], s2[64], s3[10], red[2];
    const int g = blockIdx.x, t = threadIdx.x;
    sz[t] = r[g * 256 + t];
    sz[t + 128] = r[g * 256 + 128 + t];
    __syncthreads();
    float acc = l1b[t];
    for (int i = 0; i < 256; i++) acc = fmaf(sz[i], l1W[i * 128 + t], acc);
    s1[t] = fmaxf(acc, 0.0f);
    __syncthreads();
    if (t < 64) {
        float a2 = l2b[t];
        for (int i = 0; i < 128; i++) a2 = fmaf(s1[i], l2W[i * 64 + t], a2);
        s2[t] = fmaxf(a2, 0.0f);
    }
    __syncthreads();
    if (t < 10) {
        float a3 = l3b[t];
        for (int i = 0; i < 64; i++) a3 = fmaf(s2[i], l3W[i * 10 + t], a3);
        s3[t] = a3;
    }
    __syncthreads();
    if (t == 0) {
        float m = -1e30f;
        for (int c = 0; c < 10; c++) m = fmaxf(m, s3[c]);
        float sum = 0.0f;
        for (int c = 0; c < 10; c++) sum += expf(s3[c] - m);
        red[0] = m;
        red[1] = logf(sum);
    }
    __syncthreads();
    if (t < 10) out[g * 10 + t] = s3[t] - red[0] - red[1];
}

// ---------------------------------------------------------------------------
extern "C" void kernel_launch(void* const* d_in, const int* in_sizes, int n_in,
                              void* d_out, int out_size, void* d_ws, size_t ws_size,
                              hipStream_t stream) {
    const float* x    = (const float*)d_in[0];
    const int* src0   = (const int*)d_in[1];
    const int* dst0   = (const int*)d_in[2];
    const float* W1   = (const float*)d_in[3];
    const float* b1   = (const float*)d_in[4];
    const float* A1   = (const float*)d_in[5];
    const float* ps1W = (const float*)d_in[6];
    const float* ps1b = (const float*)d_in[7];
    const float* W2   = (const float*)d_in[8];
    const float* b2   = (const float*)d_in[9];
    const float* A2   = (const float*)d_in[10];
    const float* ps2W = (const float*)d_in[11];
    const float* ps2b = (const float*)d_in[12];
    const float* W3   = (const float*)d_in[13];
    const float* b3   = (const float*)d_in[14];
    const float* A3   = (const float*)d_in[15];
    const float* ps3W = (const float*)d_in[16];
    const float* ps3b = (const float*)d_in[17];
    const float* l1W  = (const float*)d_in[18];
    const float* l1b  = (const float*)d_in[19];
    const float* l2W  = (const float*)d_in[20];
    const float* l2b  = (const float*)d_in[21];
    const float* l3W  = (const float*)d_in[22];
    const float* l3b  = (const float*)d_in[23];
    float* out = (float*)d_out;

    char* ws = (char*)d_ws;
    size_t o = 0;
    auto alloc = [&](size_t bytes) -> void* {
        void* p = ws + o;
        o += (bytes + 255) & ~(size_t)255;
        return p;
    };
    float* hproj   = (float*)alloc((size_t)N0 * FDIM * 4);
    float* hact    = (float*)alloc((size_t)N0 * FDIM * 4);
    float* xn      = (float*)alloc((size_t)N0 * FDIM * 4);
    int*   cnt     = (int*)alloc(N0 * 4);
    float* dinv    = (float*)alloc(N0 * 4);
    int*   rowptr  = (int*)alloc(N0 * 4);
    int*   rowcnt  = (int*)alloc(N0 * 4);
    int*   csr_src = (int*)alloc(EDG * 4);
    float* cs      = (float*)alloc(N0 * 4);
    int*   nmap    = (int*)alloc(N0 * 4);
    int*   perm    = (int*)alloc(BGR * K1 * 4);
    float* mult    = (float*)alloc(BGR * K1 * 4);
    float* r       = (float*)alloc(BGR * 256 * 4);
    int*   se1     = (int*)alloc(EDG * 4);
    int*   de1     = (int*)alloc(EDG * 4);
    int*   se2     = (int*)alloc(EDG * 4);
    int*   de2     = (int*)alloc(EDG * 4);
    float* pmax    = (float*)alloc((size_t)(BGR * K1 / PGJ) * FDIM * 4);
    float* psum    = (float*)alloc((size_t)(BGR * K1 / PGJ) * FDIM * 4);

    // ---------------- Stage 1: n=32768, nper=1024, k=512 ----------------
    zero_int<<<N0 / 256, 256, 0, stream>>>(cnt, N0);
    count_kernel<<<EDG / 256, 256, 0, stream>>>(src0, dst0, cnt);
    scan_kernel<<<BGR, 256, 0, stream>>>(cnt, NPER0, dinv, rowptr, rowcnt);
    scatter_kernel<<<EDG / 256, 256, 0, stream>>>(src0, dst0, rowptr, cnt, csr_src);
    proj_kernel<<<N0 / 32, 128, 0, stream>>>(x, W1, hproj);
    agg_kernel<<<N0 / 4, 256, 0, stream>>>(hproj, b1, dinv, rowptr, rowcnt, csr_src, hact, NPER0);
    attcs_kernel<<<N0 / 4, 256, 0, stream>>>(hact, A1, ps1W, cs);
    topk_kernel<<<BGR, 256, 0, stream>>>(cs, dinv, rowptr, rowcnt, csr_src, ps1b,
                                         NPER0, K1, nmap, perm, mult);
    poolgather_kernel<<<BGR * K1 / PGJ, 128, 0, stream>>>(hact, perm, mult, K1, xn, pmax, psum);
    readout_reduce<<<BGR, 128, 0, stream>>>(pmax, psum, K1 / PGJ, K1, r, 0);

    // ---------------- Stage 2: n=16384, nper=512, k=256 ----------------
    const int n1 = BGR * K1;
    zero_int<<<(n1 + 255) / 256, 256, 0, stream>>>(cnt, n1);
    remap_kernel<<<EDG / 256, 256, 0, stream>>>(src0, dst0, nmap, se1, de1, cnt);
    scan_kernel<<<BGR, 256, 0, stream>>>(cnt, K1, dinv, rowptr, rowcnt);
    scatter_kernel<<<EDG / 256, 256, 0, stream>>>(se1, de1, rowptr, cnt, csr_src);
    proj_kernel<<<n1 / 32, 128, 0, stream>>>(xn, W2, hproj);
    agg_kernel<<<n1 / 4, 256, 0, stream>>>(hproj, b2, dinv, rowptr, rowcnt, csr_src, hact, K1);
    attcs_kernel<<<n1 / 4, 256, 0, stream>>>(hact, A2, ps2W, cs);
    topk_kernel<<<BGR, 256, 0, stream>>>(cs, dinv, rowptr, rowcnt, csr_src, ps2b,
                                         K1, K2, nmap, perm, mult);
    poolgather_kernel<<<BGR * K2 / PGJ, 128, 0, stream>>>(hact, perm, mult, K2, xn, pmax, psum);
    readout_reduce<<<BGR, 128, 0, stream>>>(pmax, psum, K2 / PGJ, K2, r, 1);

    // ---------------- Stage 3: n=8192, nper=256, k=128 ----------------
    const int n2 = BGR * K2;
    zero_int<<<(n2 + 255) / 256, 256, 0, stream>>>(cnt, n2);
    remap_kernel<<<EDG / 256, 256, 0, stream>>>(se1, de1, nmap, se2, de2, cnt);
    scan_kernel<<<BGR, 256, 0, stream>>>(cnt, K2, dinv, rowptr, rowcnt);
    scatter_kernel<<<EDG / 256, 256, 0, stream>>>(se2, de2, rowptr, cnt, csr_src);
    proj_kernel<<<n2 / 32, 128, 0, stream>>>(xn, W3, hproj);
    agg_kernel<<<n2 / 4, 256, 0, stream>>>(hproj, b3, dinv, rowptr, rowcnt, csr_src, hact, K2);
    attcs_kernel<<<n2 / 4, 256, 0, stream>>>(hact, A3, ps3W, cs);
    topk_kernel<<<BGR, 256, 0, stream>>>(cs, dinv, rowptr, rowcnt, csr_src, ps3b,
                                         K2, K3, nmap, perm, mult);
    poolgather_kernel<<<BGR * K3 / PGJ, 128, 0, stream>>>(hact, perm, mult, K3, xn, pmax, psum);
    readout_reduce<<<BGR, 128, 0, stream>>>(pmax, psum, K3 / PGJ, K3, r, 1);

    // ---------------- Final MLP ----------------
    final_mlp<<<BGR, 128, 0, stream>>>(r, l1W, l1b, l2W, l2b, l3W, l3b, out);

    (void)in_sizes; (void)n_in; (void)out_size; (void)ws_size;
}